// Round 3
// baseline (2212.268 us; speedup 1.0000x reference)
//
#include <hip/hip_runtime.h>
#include <utility>
#include <cstddef>

#define NCOLS  985        // 1 + 16 + 136 + 816 + 16
#define RPW    16         // rows per wave
#define CHUNK  64         // columns per chunk
#define NCHUNK 16         // 16*64 = 1024 >= 985
#define SLABF  (RPW * CHUNK)   // 1024 floats = 4 KB per wave

// ---- compile-time combinatorial decoders (match itertools order) ----
constexpr int pair_i_f(int p){ int i=0; while (p >= 16-i){ p -= 16-i; ++i; } return i; }
constexpr int pair_j_f(int p){ int i=0; while (p >= 16-i){ p -= 16-i; ++i; } return i+p; }
constexpr int tcount(int i){ return (16-i)*(17-i)/2; }
constexpr int trip_i_f(int t){ int i=0; while (t >= tcount(i)){ t -= tcount(i); ++i; } return i; }
constexpr int trip_j_f(int t){ int i=0; while (t >= tcount(i)){ t -= tcount(i); ++i; }
                               int j=i; while (t >= 16-j){ t -= 16-j; ++j; } return j; }
constexpr int trip_k_f(int t){ int i=0; while (t >= tcount(i)){ t -= tcount(i); ++i; }
                               int j=i; while (t >= 16-j){ t -= 16-j; ++j; } return j+t; }

// ---- one output column, fully static indices -> zc stays in VGPRs ----
template<int E>
__device__ __forceinline__ float term(const float (&zc)[16]) {
  if constexpr (E >= NCOLS) {
    return 0.0f;                       // padding columns (masked at store)
  } else if constexpr (E == 0) {
    return 1.0f;
  } else if constexpr (E <= 16) {
    return zc[E-1];
  } else if constexpr (E < 17 + 136) {
    constexpr int p = E - 17;
    return zc[pair_i_f(p)] * zc[pair_j_f(p)];
  } else if constexpr (E < 17 + 136 + 816) {
    constexpr int t = E - 153;
    return (zc[trip_i_f(t)] * zc[trip_j_f(t)]) * zc[trip_k_f(t)];
  } else {
    return __sinf(zc[E - 969]);
  }
}

// 16 static terms for columns [C*64 + G*16, C*64 + G*16 + 16)
template<int C, int G>
__device__ __forceinline__ void quads(const float (&zc)[16], float4 (&t)[4]) {
  constexpr int B = C*CHUNK + G*16;
  t[0] = make_float4(term<B+ 0>(zc), term<B+ 1>(zc), term<B+ 2>(zc), term<B+ 3>(zc));
  t[1] = make_float4(term<B+ 4>(zc), term<B+ 5>(zc), term<B+ 6>(zc), term<B+ 7>(zc));
  t[2] = make_float4(term<B+ 8>(zc), term<B+ 9>(zc), term<B+10>(zc), term<B+11>(zc));
  t[3] = make_float4(term<B+12>(zc), term<B+13>(zc), term<B+14>(zc), term<B+15>(zc));
}

template<int C, bool TAIL>
__device__ __forceinline__ void do_chunk(const float (&zc)[16], float* slw,
                                         float* outp, int l, int row0, int batch) {
  const int row = l & 15;
  const int g   = l >> 4;
  const int s   = l & 3;               // row & 3 (swizzle key)
  float4 t[4];
  switch (g) {                         // 4-way static dispatch (exec-masked)
    case 0:  quads<C,0>(zc, t); break;
    case 1:  quads<C,1>(zc, t); break;
    case 2:  quads<C,2>(zc, t); break;
    default: quads<C,3>(zc, t); break;
  }
  // swizzled ds_write_b128: slot (16B units) = row*16 + g*4 + (q ^ (row&3))
  // -> per instruction 8 lanes per 4-bank window: conflict-free
  float4* sq = (float4*)slw;
  const int qb = row*16 + g*4;
  sq[qb + (0^s)] = t[0];
  sq[qb + (1^s)] = t[1];
  sq[qb + (2^s)] = t[2];
  sq[qb + (3^s)] = t[3];
  __builtin_amdgcn_sched_barrier(0);   // pin write -> read (same-wave DS is in-order)
  // transpose out: store instr r covers row r, cols 0..63 = 256 B contiguous
  #pragma unroll
  for (int r = 0; r < RPW; ++r) {
    float v = slw[r*CHUNK + (l ^ ((r&3)<<2))];   // un-swizzle; 2-way banks = free
    bool ok = true;
    if constexpr (C == NCHUNK-1) ok = (l < NCOLS - (NCHUNK-1)*CHUNK);  // l < 25
    if constexpr (TAIL)          ok = ok && (row0 + r < batch);
    if (ok) outp[(size_t)r * NCOLS] = v;
  }
  __builtin_amdgcn_sched_barrier(0);   // pin read -> next chunk's writes
}

template<bool TAIL, int... Cs>
__device__ __forceinline__ void all_chunks(const float (&zc)[16], float* slw,
                                           float* obase, int l, int row0, int batch,
                                           std::integer_sequence<int, Cs...>) {
  (do_chunk<Cs, TAIL>(zc, slw, obase + Cs*CHUNK, l, row0, batch), ...);
}

__global__ __launch_bounds__(256, 6) void sindy_kernel(const float* __restrict__ z,
                                                       const float* __restrict__ dz,
                                                       float* __restrict__ out, int batch) {
  __shared__ float slab[4][SLABF];     // 4 KB per wave, 16 KB per block

  const int w    = threadIdx.x >> 6;
  const int l    = threadIdx.x & 63;
  const int row0 = (blockIdx.x * 4 + w) * RPW;   // this wave's first row
  if (row0 >= batch) return;                     // no barriers -> safe early exit

  // each lane loads its row's 16 zc values (4 lanes per row duplicate; L1 merges)
  const int lrow = (row0 + (l & 15) < batch) ? (row0 + (l & 15)) : (batch - 1);
  float zc[16];
  {
    const float4* zp = (const float4*)(z  + (size_t)lrow * 8);
    const float4* dp = (const float4*)(dz + (size_t)lrow * 8);
    float4 a = zp[0], b = zp[1], c = dp[0], d = dp[1];
    zc[0]=a.x;  zc[1]=a.y;  zc[2]=a.z;  zc[3]=a.w;
    zc[4]=b.x;  zc[5]=b.y;  zc[6]=b.z;  zc[7]=b.w;
    zc[8]=c.x;  zc[9]=c.y;  zc[10]=c.z; zc[11]=c.w;
    zc[12]=d.x; zc[13]=d.y; zc[14]=d.z; zc[15]=d.w;
  }

  float* slw   = slab[w];
  float* obase = out + (size_t)row0 * NCOLS + l;

  if (row0 + RPW <= batch) {
    all_chunks<false>(zc, slw, obase, l, row0, batch,
                      std::make_integer_sequence<int, NCHUNK>{});
  } else {
    all_chunks<true>(zc, slw, obase, l, row0, batch,
                     std::make_integer_sequence<int, NCHUNK>{});
  }
}

extern "C" void kernel_launch(void* const* d_in, const int* in_sizes, int n_in,
                              void* d_out, int out_size, void* d_ws, size_t ws_size,
                              hipStream_t stream) {
  const float* z  = (const float*)d_in[0];
  const float* dz = (const float*)d_in[1];
  float* out = (float*)d_out;
  const int batch = in_sizes[0] / 8;   // LATENT_DIM = 8

  const int blocks = (batch + 63) / 64;   // 64 rows per block (4 waves x 16 rows)
  sindy_kernel<<<blocks, 256, 0, stream>>>(z, dz, out, batch);
}

// Round 4
// 127.015 us; speedup vs baseline: 17.4173x; 17.4173x over previous
//
#include <hip/hip_runtime.h>
#include <cstddef>

#define NDIM   16
#define NTAB   969      // cols 0..968: 1 + 16 + 136 + 816
#define NCOLS  985      // + 16 sine columns
#define RPW    16       // rows per wave
#define SLOT   17       // 16 zc values + sentinel 1.0f at index 16

__global__ __launch_bounds__(256) void sindy_kernel(const float* __restrict__ z,
                                                    const float* __restrict__ dz,
                                                    float* __restrict__ out, int batch) {
  __shared__ unsigned short tab[NTAB];
  __shared__ float zs[4][SLOT];        // one 17-float slot per wave (wave-private)

  // ---- build packed index table: col -> i | j<<5 | k<<10  (index 16 == 1.0f) ----
  for (int e = threadIdx.x; e < NTAB; e += 256) {
    int i = 16, j = 16, k = 16;
    if (e >= 1 && e <= 16) {
      i = e - 1;
    } else if (e >= 17 && e < 153) {
      int p = e - 17; i = 0;
      while (p >= 16 - i) { p -= 16 - i; ++i; }
      j = i + p;
    } else if (e >= 153) {
      int t = e - 153; i = 0;
      for (;;) { int c = (16 - i) * (17 - i) / 2; if (t < c) break; t -= c; ++i; }
      j = i;
      while (t >= 16 - j) { t -= 16 - j; ++j; }
      k = j + t;
    }
    tab[e] = (unsigned short)(i | (j << 5) | (k << 10));
  }
  __syncthreads();   // the ONLY barrier in the kernel

  const int w = threadIdx.x >> 6;
  const int l = threadIdx.x & 63;
  float* zr = zs[w];

  const int rbase = (blockIdx.x * 4 + w) * RPW;   // this wave's first row

  for (int rr = 0; rr < RPW; ++rr) {
    const int row = rbase + rr;
    if (row >= batch) break;                      // wave-uniform exit

    // stage this row's 16 zc values + sentinel into the wave-private slot.
    // Same-wave DS ops execute in order; no barrier needed, no inter-wave sharing.
    if (l < SLOT) {
      float v = 1.0f;
      if (l < 8)       v = z[(size_t)row * 8 + l];
      else if (l < 16) v = dz[(size_t)row * 8 + (l - 8)];
      zr[l] = v;
    }

    float* orow = out + (size_t)row * NCOLS;

    // 15 fully uniform iterations: cols 0..959, zero branching.
    // Gathers hit 17 consecutive banks (all distinct); same-address reads broadcast.
    #pragma unroll
    for (int it = 0; it < 15; ++it) {
      const int col = it * 64 + l;
      const unsigned pk = tab[col];
      const float v = zr[pk & 31] * zr[(pk >> 5) & 31] * zr[(pk >> 10) & 31];
      orow[col] = v;                               // 256 B contiguous per wave
    }

    // tail: cols 960..984 (9 table terms + 16 sines), lanes 0..24
    if (l < NCOLS - 960) {
      const int col = 960 + l;
      float v;
      if (col < NTAB) {
        const unsigned pk = tab[col];
        v = zr[pk & 31] * zr[(pk >> 5) & 31] * zr[(pk >> 10) & 31];
      } else {
        v = __sinf(zr[col - NTAB]);
      }
      orow[col] = v;
    }
  }
}

extern "C" void kernel_launch(void* const* d_in, const int* in_sizes, int n_in,
                              void* d_out, int out_size, void* d_ws, size_t ws_size,
                              hipStream_t stream) {
  const float* z  = (const float*)d_in[0];
  const float* dz = (const float*)d_in[1];
  float* out = (float*)d_out;
  const int batch = in_sizes[0] / 8;   // LATENT_DIM = 8

  // 64 rows per block (4 waves x 16 rows) -> 2048 blocks = 8 blocks/CU, fully resident
  const int blocks = (batch + 4 * RPW - 1) / (4 * RPW);
  sindy_kernel<<<blocks, 256, 0, stream>>>(z, dz, out, batch);
}